// Round 1
// 4230.919 us; speedup vs baseline: 1.4301x; 1.4301x over previous
//
#include <hip/hip_runtime.h>
#include <math.h>

// Problem constants (fixed by reference)
static constexpr int NN   = 16384;   // nodes
static constexpr int D_IN = 512;
static constexpr int D_H1 = 256;
static constexpr int D_H2 = 128;

// ---------------------------------------------------------------------------
// fp32 tiled GEMM: C (+)= A[M,K] @ B[K,N], row-major.
// 256 threads, BM=BN=128, TM=TN=8.  Split-K via gridDim.z: each z-slice
// covers kLen of K and (ATOMIC) accumulates with global_atomic_add_f32.
// RELU_A applies relu to A elements on load (moves step-2's relu into
// step-3's read so atomic partials stay linear).
// Wave-local 8x8 thread sub-grid keeps both LDS fragment reads 2-way (free).
// ---------------------------------------------------------------------------
template<int BM, int BN, int BK, int TM, int TN, bool RELU_A, bool ATOMIC>
__global__ __launch_bounds__((BM/TM)*(BN/TN), 4)
void gemm_kernel(const float* __restrict__ A, const float* __restrict__ B,
                 float* __restrict__ C, int M, int N, int K, int kLen)
{
    constexpr int THREADS = (BM/TM)*(BN/TN);
    static_assert(THREADS == 256 && BM/TM == 16 && BN/TN == 16,
                  "wave mapping assumes 16x16 thread grid");
    constexpr int PAD = 4;                 // 16B-aligned b128 reads, breaks
                                           // worst-case transpose-store conflicts
    __shared__ float sA[BK][BM+PAD];       // A tile transposed [k][m]
    __shared__ float sB[BK][BN];           // B tile natural [k][n]

    const int tid  = threadIdx.x;
    const int lane = tid & 63;
    const int w    = tid >> 6;
    // wave covers an 8x8 block of thread-tiles: LDS reads hit 8 consecutive
    // tm (or tn) values -> addresses stride 32B -> 2-way bank alias (free).
    const int tm = (w >> 1) * 8 + (lane >> 3);   // 0..15
    const int tn = (w & 1)  * 8 + (lane & 7);    // 0..15

    const int rowBase = blockIdx.x * BM;
    const int colBase = blockIdx.y * BN;
    const int kOff    = blockIdx.z * kLen;

    float acc[TM][TN];
#pragma unroll
    for (int i = 0; i < TM; ++i)
#pragma unroll
        for (int j = 0; j < TN; ++j) acc[i][j] = 0.f;

    constexpr int AF4_PER = (BM*BK/4)/THREADS;
    constexpr int BF4_PER = (BK*BN/4)/THREADS;

    const int kEnd = kOff + kLen;
    for (int k0 = kOff; k0 < kEnd; k0 += BK) {
        // ---- stage A tile (BM x BK), transpose into LDS ----
#pragma unroll
        for (int it = 0; it < AF4_PER; ++it) {
            const int q  = tid + it*THREADS;
            const int r  = q / (BK/4);
            const int c4 = q % (BK/4);
            float4 av = *reinterpret_cast<const float4*>(
                &A[(size_t)(rowBase + r)*K + (k0 + 4*c4)]);
            if (RELU_A) {
                av.x = fmaxf(av.x, 0.f); av.y = fmaxf(av.y, 0.f);
                av.z = fmaxf(av.z, 0.f); av.w = fmaxf(av.w, 0.f);
            }
            sA[4*c4+0][r] = av.x;
            sA[4*c4+1][r] = av.y;
            sA[4*c4+2][r] = av.z;
            sA[4*c4+3][r] = av.w;
        }
        // ---- stage B tile (BK x BN) ----
#pragma unroll
        for (int it = 0; it < BF4_PER; ++it) {
            const int q  = tid + it*THREADS;
            const int r  = q / (BN/4);
            const int c4 = q % (BN/4);
            *reinterpret_cast<float4*>(&sB[r][4*c4]) =
                *reinterpret_cast<const float4*>(
                    &B[(size_t)(k0 + r)*N + (colBase + 4*c4)]);
        }
        __syncthreads();

        // ---- 8x8 register-tile FMA over BK ----
#pragma unroll
        for (int k = 0; k < BK; ++k) {
            float a[TM], b[TN];
#pragma unroll
            for (int i = 0; i < TM; i += 4)
                *reinterpret_cast<float4*>(&a[i]) =
                    *reinterpret_cast<const float4*>(&sA[k][tm*TM + i]);
#pragma unroll
            for (int j = 0; j < TN; j += 4)
                *reinterpret_cast<float4*>(&b[j]) =
                    *reinterpret_cast<const float4*>(&sB[k][tn*TN + j]);
#pragma unroll
            for (int i = 0; i < TM; ++i)
#pragma unroll
                for (int j = 0; j < TN; ++j)
                    acc[i][j] = fmaf(a[i], b[j], acc[i][j]);
        }
        __syncthreads();
    }

    // ---- epilogue ----
    if (ATOMIC) {
#pragma unroll
        for (int i = 0; i < TM; ++i) {
            const size_t off = (size_t)(rowBase + tm*TM + i)*N + colBase + tn*TN;
#pragma unroll
            for (int j = 0; j < TN; ++j)
                unsafeAtomicAdd(&C[off + j], acc[i][j]);
        }
    } else {
#pragma unroll
        for (int i = 0; i < TM; ++i) {
            const size_t off = (size_t)(rowBase + tm*TM + i)*N + colBase + tn*TN;
#pragma unroll
            for (int j = 0; j < TN; j += 4) {
                float4 o;
                o.x = acc[i][j+0]; o.y = acc[i][j+1];
                o.z = acc[i][j+2]; o.w = acc[i][j+3];
                *reinterpret_cast<float4*>(&C[off + j]) = o;
            }
        }
    }
}

// zero-fill (float4 grid-stride) — init for atomic split-K accumulation
__global__ void zero_kernel(float4* __restrict__ p, int n4)
{
    int i = blockIdx.x*blockDim.x + threadIdx.x;
    const int stride = gridDim.x*blockDim.x;
    const float4 zv = make_float4(0.f, 0.f, 0.f, 0.f);
    for (; i < n4; i += stride) p[i] = zv;
}

// v[r] = sum_c Wtwo[r,c] * Wthree[c],  r in [0,256), c in [0,128)
__global__ void prep_v_kernel(const float* __restrict__ Wtwo,
                              const float* __restrict__ W3,
                              float* __restrict__ v)
{
    const int r = threadIdx.x;   // 256 threads
    float s = 0.f;
    for (int c = 0; c < D_H2; ++c) s = fmaf(Wtwo[r*D_H2 + c], W3[c], s);
    v[r] = s;
}

// Fused decode: out[e] = sigmoid( relu(zi).v[0:128] + relu(zj).v[128:256]
//                               + (zi*zj).W3[128:256] )
// One wave per edge; lane l covers channels {l, l+64}.
__global__ __launch_bounds__(256)
void decode_kernel(const float* __restrict__ z,
                   const int* __restrict__ e1, const int* __restrict__ e2,
                   const float* __restrict__ v, const float* __restrict__ W3,
                   float* __restrict__ out, int E)
{
    const int lane = threadIdx.x & 63;
    const int wave = (blockIdx.x * blockDim.x + threadIdx.x) >> 6;
    const int nWaves = (gridDim.x * blockDim.x) >> 6;

    const float v0 = v[lane],        v1 = v[lane + 64];
    const float v2 = v[lane + 128],  v3 = v[lane + 192];
    const float w0 = W3[D_H2 + lane], w1 = W3[D_H2 + 64 + lane];

    const int total = 2*E;
    for (int idx = wave; idx < total; idx += nWaves) {
        const int* ep = (idx < E) ? (e1 + 2*(size_t)idx)
                                  : (e2 + 2*(size_t)(idx - E));
        const int i = ep[0], j = ep[1];
        const float* zi = z + (size_t)i * D_H2;
        const float* zj = z + (size_t)j * D_H2;
        const float zi0 = zi[lane], zi1 = zi[lane + 64];
        const float zj0 = zj[lane], zj1 = zj[lane + 64];

        float t = fmaxf(zi0, 0.f)*v0 + fmaxf(zi1, 0.f)*v1
                + fmaxf(zj0, 0.f)*v2 + fmaxf(zj1, 0.f)*v3
                + zi0*zj0*w0 + zi1*zj1*w1;

#pragma unroll
        for (int o = 32; o >= 1; o >>= 1) t += __shfl_xor(t, o, 64);

        if (lane == 0) out[idx] = 1.0f / (1.0f + expf(-t));
    }
}

extern "C" void kernel_launch(void* const* d_in, const int* in_sizes, int n_in,
                              void* d_out, int out_size, void* d_ws, size_t ws_size,
                              hipStream_t stream)
{
    const float* x    = (const float*)d_in[0];
    const float* adj  = (const float*)d_in[1];
    const float* W1   = (const float*)d_in[2];
    const float* W2   = (const float*)d_in[3];
    const float* Wtwo = (const float*)d_in[4];
    const float* W3   = (const float*)d_in[5];
    const int*   e1   = (const int*)d_in[6];
    const int*   e2   = (const int*)d_in[7];
    float* out = (float*)d_out;
    const int E = in_sizes[6] / 2;   // 500000

    // workspace layout (bytes):
    //   [0, 16.78M)        xw (16384x256)  -> reused as z (16384x128) after step 2
    //   [16.78M, 33.55M)   h  (16384x256, pre-relu; relu applied on step-3 load)
    //   [33.55M, 41.94M)   hw (16384x128)
    //   [41.94M, +1KB)     v  (256)
    char* ws = (char*)d_ws;
    float* xw = (float*)(ws);
    float* h  = (float*)(ws + (size_t)16777216);
    float* hw = (float*)(ws + (size_t)33554432);
    float* v  = (float*)(ws + (size_t)41943040);
    float* z  = xw;                       // xw dead after step 2

    // 0) zero xw/h/hw (atomic split-K accumulators); 42MB ≈ 7µs
    zero_kernel<<<512, 256, 0, stream>>>((float4*)ws, 41943040/16);
    // 1) xw = x @ W1                      (M=16384, N=256, K=512) direct store
    gemm_kernel<128,128,32,8,8,false,false><<<dim3(128,2,1), 256, 0, stream>>>(
        x, W1, xw, NN, D_H1, D_IN, D_IN);
    // 2) h += adj @ xw   split-K x4 atomic (dominant, 137 GFLOP; 1024 blocks
    //    = 4 blocks/CU x 4 waves = 16 waves/CU, the VGPR occupancy ceiling)
    gemm_kernel<128,128,32,8,8,false,true><<<dim3(128,2,4), 256, 0, stream>>>(
        adj, xw, h, NN, D_H1, NN, NN/4);
    // 3) hw += relu(h) @ W2  (relu fused into A-load), split-K x2 atomic
    gemm_kernel<128,128,32,8,8,true,true><<<dim3(128,1,2), 256, 0, stream>>>(
        h, W2, hw, NN, D_H2, D_H1, D_H1/2);
    // 3b) zero z (aliases xw; xw dead after step 2)
    zero_kernel<<<256, 256, 0, stream>>>((float4*)z, NN*D_H2/4);
    // 4) z += adj @ hw   split-K x8 atomic (68.7 GFLOP, 1024 blocks)
    gemm_kernel<128,128,32,8,8,false,true><<<dim3(128,1,8), 256, 0, stream>>>(
        adj, hw, z, NN, D_H2, NN, NN/8);
    // 5) v = Wtwo @ W3[:128]  (decode algebraic fusion)
    prep_v_kernel<<<1, 256, 0, stream>>>(Wtwo, W3, v);
    // 6) decode both edge lists -> sigmoid logits
    decode_kernel<<<2048, 256, 0, stream>>>(z, e1, e2, v, W3, out, E);
}